// Round 19
// baseline (47.261 us; speedup 1.0000x reference)
//
#include <hip/hip_runtime.h>
#include <math.h>

#define E_N 40000
#define D_N 200
#define L_N 100
#define K_N 300
#define B_N 32

typedef float  f32x4 __attribute__((ext_vector_type(4)));
typedef short  s16x8 __attribute__((ext_vector_type(8)));
typedef unsigned int u32x4 __attribute__((ext_vector_type(4)));

// ws layout (f32 units) — unchanged:
//  sh  [100][32] @ 0      r_l*(num_lit[e1_b,l]-c_l)
//  w   [100][32] @ 3200   nf_w[rel_b,l]
//  nr  [100]     @ 6400   -r_l,  r_l = sqrt(log2e/var_l)
//  s0  [32]      @ 6500   q[b,:].b_lit   (pad to 6532)
//  pA  u16[2][10][64][8] @ 6532   p in MFMA A-frag layout, bf16, zero-pad k>=300
#define WS_SH 0
#define WS_W  3200
#define WS_NR 6400
#define WS_S0 6500
#define WS_PA 6532

// smem layout (f32): tables [0,6532) + mlit buf0 @ 6532 + mlit buf1 @ 9732
// (3200 f32 each). cbuf for chunk c ALIASES buf[c] (dead after that chunk's
// RBF; barrier separates last read from first write — r14..r18-proven).
#define SM_ML   6532
#define SM_MLSZ 3200
#define SM_TOT  12932    // 51728 B -> 3 blocks/CU -> 625 blocks co-resident

__device__ inline float fast_exp2(float x) {
#if __has_builtin(__builtin_amdgcn_exp2f)
    return __builtin_amdgcn_exp2f(x);
#else
    return exp2f(x);
#endif
}
__device__ inline float fast_rcp(float x) {
#if __has_builtin(__builtin_amdgcn_rcpf)
    return __builtin_amdgcn_rcpf(x);
#else
    return 1.0f / x;
#endif
}
__device__ inline ushort f2bf(float f) {        // RNE f32->bf16 (prep only)
    uint u = __builtin_bit_cast(uint, f);
    u += 0x7fffu + ((u >> 16) & 1u);
    return (ushort)(u >> 16);
}
// r16-proven: hardware RNE pack, 1 instr per 2 elements.
__device__ inline s16x8 pack_bf8(f32x4 lo, f32x4 hi) {
    uint r0, r1, r2, r3;
    asm("v_cvt_pk_bf16_f32 %0, %1, %2" : "=v"(r0) : "v"(lo[0]), "v"(lo[1]));
    asm("v_cvt_pk_bf16_f32 %0, %1, %2" : "=v"(r1) : "v"(lo[2]), "v"(lo[3]));
    asm("v_cvt_pk_bf16_f32 %0, %1, %2" : "=v"(r2) : "v"(hi[0]), "v"(hi[1]));
    asm("v_cvt_pk_bf16_f32 %0, %1, %2" : "=v"(r3) : "v"(hi[2]), "v"(hi[3]));
    u32x4 r = {r0, r1, r2, r3};
    return __builtin_bit_cast(s16x8, r);
}

__global__ __launch_bounds__(320) void prep_kernel(
    const int* __restrict__ e1, const int* __restrict__ rel,
    const float* __restrict__ emb_e, const float* __restrict__ emb_rel,
    const float* __restrict__ num_lit, const float* __restrict__ num_lit_norm,
    const float* __restrict__ W, const float* __restrict__ b_lit,
    const float* __restrict__ c, const float* __restrict__ var,
    const float* __restrict__ nf_w, float* __restrict__ ws)
{
    const int b = blockIdx.x;
    const int t = threadIdx.x;
    __shared__ float q[D_N];
    const int e1b = e1[b];
    const int rb  = rel[b];

    if (t < D_N) {
        const float* wr = W + t * K_N;
        const float* er = emb_e + (long)e1b * D_N;
        const float* nl = num_lit_norm + (long)e1b * L_N;
        float s0_ = b_lit[t], s1_ = 0.f, s2_ = 0.f, s3_ = 0.f;
        for (int k = 0; k < D_N; k += 4) {
            s0_ += er[k+0] * wr[k+0]; s1_ += er[k+1] * wr[k+1];
            s2_ += er[k+2] * wr[k+2]; s3_ += er[k+3] * wr[k+3];
        }
        for (int k = 0; k < L_N; k += 4) {
            s0_ += nl[k+0] * wr[D_N+k+0]; s1_ += nl[k+1] * wr[D_N+k+1];
            s2_ += nl[k+2] * wr[D_N+k+2]; s3_ += nl[k+3] * wr[D_N+k+3];
        }
        q[t] = ((s0_ + s1_) + (s2_ + s3_)) * emb_rel[rb * D_N + t];
    }
    __syncthreads();

    {   // p[b,k] = sum_d q[d]*W[d,k]  -> bf16, A-frag layout
        float pk = 0.f;
        if (t < K_N) {
            float a0 = 0.f, a1 = 0.f, a2 = 0.f, a3 = 0.f;
            for (int d = 0; d < D_N; d += 4) {
                a0 += q[d+0] * W[(d+0) * K_N + t];
                a1 += q[d+1] * W[(d+1) * K_N + t];
                a2 += q[d+2] * W[(d+2) * K_N + t];
                a3 += q[d+3] * W[(d+3) * K_N + t];
            }
            pk = (a0 + a1) + (a2 + a3);
        }
        const int s  = t >> 5;
        const int g  = (t >> 3) & 3;
        const int j  = t & 7;
        const int mt = b >> 4;
        const int ln = (g << 4) | (b & 15);
        ushort* pa = (ushort*)(ws + WS_PA);
        pa[((mt * 10 + s) * 64 + ln) * 8 + j] = f2bf(pk);
    }

    if (t < L_N) {
        const float r = sqrtf(1.4426950408889634f / var[t]);
        ws[WS_SH + t * 32 + b] = r * (num_lit[(long)e1b * L_N + t] - c[t]);
        ws[WS_W  + t * 32 + b] = nf_w[rb * L_N + t];
        if (b == 0) ws[WS_NR + t] = -r;
    }
    if (t == 300) {
        float s = 0.f;
        for (int d = 0; d < D_N; ++d) s += q[d] * b_lit[d];
        ws[WS_S0 + b] = s;
    }
}

// Persistent blocks: 625 blocks x 256 threads, each runs 2 chunks of 32 e-rows
// (625*2*32 = 40000 exactly; single co-resident generation, 3 blocks/CU).
// Tables staged ONCE; chunk-1 mlit DMA issued before chunk-0 MFMA and hidden
// under chunk-0's RBF. Waves = (mt, h) as r11. cbuf aliases active mlit buf.
__global__ __launch_bounds__(256, 3) void score_kernel(
    const float* __restrict__ emb_e, const float* __restrict__ num_lit,
    const float* __restrict__ num_lit_norm, const float* __restrict__ ws,
    float* __restrict__ out)
{
    __shared__ float smem[SM_TOT];

    const int lane = threadIdx.x & 63;
    const int wv   = threadIdx.x >> 6;
    const int mt   = wv & 1;                   // b-half
    const int h    = wv >> 1;                  // l/K half
    const int er   = lane & 15;
    const int g    = lane >> 4;
    const int b0   = mt * 16 + 4 * g;

    // ---- A fragments (chunk-invariant): issue first ----
    s16x8 afr[5];
    {
        const s16x8* pAg = (const s16x8*)(ws + WS_PA);
#pragma unroll
        for (int i = 0; i < 5; ++i) afr[i] = pAg[(mt * 10 + h * 5 + i) * 64 + lane];
    }

    // ---- initial DMA stage: tables (1633 f32x4) + chunk-0 mlit (800 f32x4) ----
    {
        const f32x4* s4  = (const f32x4*)ws;
        const f32x4* ml4 = (const f32x4*)(num_lit + (long)(blockIdx.x * 2) * 32 * L_N);
        f32x4* d4 = (f32x4*)smem;
        for (int i = threadIdx.x; i < 2433; i += 256) {
            const f32x4* src = (i < 1633) ? (s4 + i) : (ml4 + (i - 1633));
            __builtin_amdgcn_global_load_lds((const __attribute__((address_space(1))) void*)src,
                                             (__attribute__((address_space(3))) void*)(d4 + i),
                                             16, 0, 0);
        }
    }
    __syncthreads();

    // ---- bias term from LDS (chunk-invariant) ----
    const f32x4 s0v = *(const f32x4*)(smem + WS_S0 + b0);

#pragma unroll
    for (int c = 0; c < 2; ++c) {
        const int e_base = (blockIdx.x * 2 + c) * 32;
        const int ea = e_base + er;
        const int eb = ea + 16;

        // ---- prefetch chunk-1 mlit into buf1 (flies under chunk-0 RBF) ----
        if (c == 0) {
            const f32x4* ml4 = (const f32x4*)(num_lit + (long)(e_base + 32) * L_N);
            f32x4* d4 = (f32x4*)(smem + SM_ML + SM_MLSZ);
            for (int i = threadIdx.x; i < 800; i += 256)
                __builtin_amdgcn_global_load_lds((const __attribute__((address_space(1))) void*)(ml4 + i),
                                                 (__attribute__((address_space(3))) void*)(d4 + i),
                                                 16, 0, 0);
        }

        // ---- acc init ----
        f32x4 acc_a = {0.f, 0.f, 0.f, 0.f};
        f32x4 acc_b = {0.f, 0.f, 0.f, 0.f};
        if (h == 0) { acc_a = s0v; acc_b = s0v; }

        const float* embrA = emb_e        + (long)ea * D_N;
        const float* litnA = num_lit_norm + (long)ea * L_N;
        const float* embrB = emb_e        + (long)eb * D_N;
        const float* litnB = num_lit_norm + (long)eb * L_N;

        // ---- score_l via MFMA, K-steps [5h, 5h+5), two e-tiles ----
#pragma unroll
        for (int i = 0; i < 4; ++i) {
            const int k0 = 32 * (h * 5 + i) + 8 * g;
            const float* bpA = (k0 < 200) ? (embrA + k0) : (litnA + (k0 - 200));
            const float* bpB = (k0 < 200) ? (embrB + k0) : (litnB + (k0 - 200));
            f32x4 loA = *(const f32x4*)bpA;
            f32x4 hiA = *(const f32x4*)(bpA + 4);
            f32x4 loB = *(const f32x4*)bpB;
            f32x4 hiB = *(const f32x4*)(bpB + 4);
            acc_a = __builtin_amdgcn_mfma_f32_16x16x32_bf16(afr[i], pack_bf8(loA, hiA), acc_a, 0, 0, 0);
            acc_b = __builtin_amdgcn_mfma_f32_16x16x32_bf16(afr[i], pack_bf8(loB, hiB), acc_b, 0, 0, 0);
        }
        if (h == 0) {       // step s=4: k0 = 128+8g, pure embr
            const int k0 = 128 + 8 * g;
            f32x4 loA = *(const f32x4*)(embrA + k0);
            f32x4 hiA = *(const f32x4*)(embrA + k0 + 4);
            f32x4 loB = *(const f32x4*)(embrB + k0);
            f32x4 hiB = *(const f32x4*)(embrB + k0 + 4);
            acc_a = __builtin_amdgcn_mfma_f32_16x16x32_bf16(afr[4], pack_bf8(loA, hiA), acc_a, 0, 0, 0);
            acc_b = __builtin_amdgcn_mfma_f32_16x16x32_bf16(afr[4], pack_bf8(loB, hiB), acc_b, 0, 0, 0);
        } else {            // step s=9: k = 288..319 (real lit 88..99; A zero-pads k>=300)
            f32x4 z = {0.f, 0.f, 0.f, 0.f};
            f32x4 loA = z, hiA = z, loB = z, hiB = z;
            if (g == 0)      { loA = *(const f32x4*)(litnA + 88); hiA = *(const f32x4*)(litnA + 92);
                               loB = *(const f32x4*)(litnB + 88); hiB = *(const f32x4*)(litnB + 92); }
            else if (g == 1) { loA = *(const f32x4*)(litnA + 96);
                               loB = *(const f32x4*)(litnB + 96); }
            acc_a = __builtin_amdgcn_mfma_f32_16x16x32_bf16(afr[4], pack_bf8(loA, hiA), acc_a, 0, 0, 0);
            acc_b = __builtin_amdgcn_mfma_f32_16x16x32_bf16(afr[4], pack_bf8(loB, hiB), acc_b, 0, 0, 0);
        }

        // ---- score_n: RBF on buf[c], lc in [13h, h?25:13) ----
        const int lc0 = h ? 13 : 0;
        const int lcE = h ? 25 : 13;
        const float* mlA = smem + SM_ML + c * SM_MLSZ + er * L_N;
        const float* mlB = mlA + 16 * L_N;
        for (int lc = lc0; lc < lcE; ++lc) {
            const f32x4 mva = *(const f32x4*)(mlA + lc * 4);
            const f32x4 mvb = *(const f32x4*)(mlB + lc * 4);
            const f32x4 nv  = *(const f32x4*)(smem + WS_NR + lc * 4);
#pragma unroll
            for (int ll = 0; ll < 4; ++ll) {
                const int l = lc * 4 + ll;
                const float rma = nv[ll] * mva[ll];
                const float rmb = nv[ll] * mvb[ll];
                f32x4 s4v = *(const f32x4*)(smem + WS_SH + l * 32 + b0);
                f32x4 w4v = *(const f32x4*)(smem + WS_W  + l * 32 + b0);
#pragma unroll
                for (int j = 0; j < 4; ++j) {
                    const float ua = rma + s4v[j];
                    const float ub = rmb + s4v[j];
                    acc_a[j] = fmaf(fast_exp2(-(ua * ua)), w4v[j], acc_a[j]);
                    acc_b[j] = fmaf(fast_exp2(-(ub * ub)), w4v[j], acc_b[j]);
                }
            }
        }

        // ---- combine + sigmoid + store (cbuf aliases buf[c]) ----
        float* cbuf = smem + SM_ML + c * SM_MLSZ;
        __syncthreads();     // RBF reads of buf[c] done; (c=0) buf1 DMA drained
        if (h) {
            *(f32x4*)(cbuf + ((0 * 2 + mt) * 64 + lane) * 4) = acc_a;
            *(f32x4*)(cbuf + ((1 * 2 + mt) * 64 + lane) * 4) = acc_b;
        }
        __syncthreads();
        if (!h) {
            const f32x4 oa = *(const f32x4*)(cbuf + ((0 * 2 + mt) * 64 + lane) * 4);
            const f32x4 ob = *(const f32x4*)(cbuf + ((1 * 2 + mt) * 64 + lane) * 4);
#pragma unroll
            for (int j = 0; j < 4; ++j) {
                const float va = acc_a[j] + oa[j];
                const float za = fast_exp2(va * -1.4426950408889634f);
                out[(long)(b0 + j) * E_N + ea] = fast_rcp(1.0f + za);
                const float vb = acc_b[j] + ob[j];
                const float zb = fast_exp2(vb * -1.4426950408889634f);
                out[(long)(b0 + j) * E_N + eb] = fast_rcp(1.0f + zb);
            }
        }
    }
}

extern "C" void kernel_launch(void* const* d_in, const int* in_sizes, int n_in,
                              void* d_out, int out_size, void* d_ws, size_t ws_size,
                              hipStream_t stream) {
    const int*   e1       = (const int*)d_in[0];
    const int*   rel      = (const int*)d_in[1];
    const float* emb_e    = (const float*)d_in[2];
    const float* emb_rel  = (const float*)d_in[3];
    const float* num_lit  = (const float*)d_in[4];
    const float* num_lit_norm = (const float*)d_in[5];
    const float* W_lit    = (const float*)d_in[6];
    const float* b_lit    = (const float*)d_in[7];
    const float* c        = (const float*)d_in[8];
    const float* var      = (const float*)d_in[9];
    const float* nf_w     = (const float*)d_in[10];
    float* out = (float*)d_out;
    float* ws  = (float*)d_ws;

    hipLaunchKernelGGL(prep_kernel, dim3(B_N), dim3(320), 0, stream,
                       e1, rel, emb_e, emb_rel, num_lit, num_lit_norm,
                       W_lit, b_lit, c, var, nf_w, ws);
    hipLaunchKernelGGL(score_kernel, dim3(625), dim3(256), 0, stream,
                       emb_e, num_lit, num_lit_norm, ws, out);
}

// Round 20
// 41.250 us; speedup vs baseline: 1.1457x; 1.1457x over previous
//
#include <hip/hip_runtime.h>
#include <math.h>

#define E_N 40000
#define D_N 200
#define L_N 100
#define K_N 300
#define B_N 32

typedef float  f32x4 __attribute__((ext_vector_type(4)));
typedef short  s16x8 __attribute__((ext_vector_type(8)));
typedef unsigned int u32x4 __attribute__((ext_vector_type(4)));

// ws layout (f32 units) — unchanged:
//  sh  [100][32] @ 0      r_l*(num_lit[e1_b,l]-c_l)
//  w   [100][32] @ 3200   nf_w[rel_b,l]
//  nr  [100]     @ 6400   -r_l,  r_l = sqrt(log2e/var_l)
//  s0  [32]      @ 6500   q[b,:].b_lit   (pad to 6532)
//  pA  u16[2][10][64][8] @ 6532   p in MFMA A-frag layout, bf16, zero-pad k>=300
#define WS_SH 0
#define WS_W  3200
#define WS_NR 6400
#define WS_S0 6500
#define WS_PA 6532

// smem layout (f32): tables copy [0,6532) + mlit[32][100] @ 6532 (3200 f32).
// cbuf[2 tile][2 mt][64 lane][4] (1024 f32) ALIASES mlit (dead after RBF;
// barrier separates last read from first write — r14..r17-proven pattern).
#define SM_ML  6532
#define SM_TOT 9732      // 38928 B -> 4 blocks/CU
#define STAGE_N 2433     // 1633 table f32x4 + 800 mlit f32x4

__device__ inline float fast_exp2(float x) {
#if __has_builtin(__builtin_amdgcn_exp2f)
    return __builtin_amdgcn_exp2f(x);
#else
    return exp2f(x);
#endif
}
__device__ inline float fast_rcp(float x) {
#if __has_builtin(__builtin_amdgcn_rcpf)
    return __builtin_amdgcn_rcpf(x);
#else
    return 1.0f / x;
#endif
}
__device__ inline ushort f2bf(float f) {        // RNE f32->bf16 (prep only)
    uint u = __builtin_bit_cast(uint, f);
    u += 0x7fffu + ((u >> 16) & 1u);
    return (ushort)(u >> 16);
}
// r16-proven: hardware RNE pack, 1 instr per 2 elements.
__device__ inline s16x8 pack_bf8(f32x4 lo, f32x4 hi) {
    uint r0, r1, r2, r3;
    asm("v_cvt_pk_bf16_f32 %0, %1, %2" : "=v"(r0) : "v"(lo[0]), "v"(lo[1]));
    asm("v_cvt_pk_bf16_f32 %0, %1, %2" : "=v"(r1) : "v"(lo[2]), "v"(lo[3]));
    asm("v_cvt_pk_bf16_f32 %0, %1, %2" : "=v"(r2) : "v"(hi[0]), "v"(hi[1]));
    asm("v_cvt_pk_bf16_f32 %0, %1, %2" : "=v"(r3) : "v"(hi[2]), "v"(hi[3]));
    u32x4 r = {r0, r1, r2, r3};
    return __builtin_bit_cast(s16x8, r);
}

__global__ __launch_bounds__(320) void prep_kernel(
    const int* __restrict__ e1, const int* __restrict__ rel,
    const float* __restrict__ emb_e, const float* __restrict__ emb_rel,
    const float* __restrict__ num_lit, const float* __restrict__ num_lit_norm,
    const float* __restrict__ W, const float* __restrict__ b_lit,
    const float* __restrict__ c, const float* __restrict__ var,
    const float* __restrict__ nf_w, float* __restrict__ ws)
{
    const int b = blockIdx.x;
    const int t = threadIdx.x;
    __shared__ float q[D_N];
    const int e1b = e1[b];
    const int rb  = rel[b];

    if (t < D_N) {
        const float* wr = W + t * K_N;
        const float* er = emb_e + (long)e1b * D_N;
        const float* nl = num_lit_norm + (long)e1b * L_N;
        float s0_ = b_lit[t], s1_ = 0.f, s2_ = 0.f, s3_ = 0.f;
        for (int k = 0; k < D_N; k += 4) {
            s0_ += er[k+0] * wr[k+0]; s1_ += er[k+1] * wr[k+1];
            s2_ += er[k+2] * wr[k+2]; s3_ += er[k+3] * wr[k+3];
        }
        for (int k = 0; k < L_N; k += 4) {
            s0_ += nl[k+0] * wr[D_N+k+0]; s1_ += nl[k+1] * wr[D_N+k+1];
            s2_ += nl[k+2] * wr[D_N+k+2]; s3_ += nl[k+3] * wr[D_N+k+3];
        }
        q[t] = ((s0_ + s1_) + (s2_ + s3_)) * emb_rel[rb * D_N + t];
    }
    __syncthreads();

    {   // p[b,k] = sum_d q[d]*W[d,k]  -> bf16, A-frag layout
        float pk = 0.f;
        if (t < K_N) {
            float a0 = 0.f, a1 = 0.f, a2 = 0.f, a3 = 0.f;
            for (int d = 0; d < D_N; d += 4) {
                a0 += q[d+0] * W[(d+0) * K_N + t];
                a1 += q[d+1] * W[(d+1) * K_N + t];
                a2 += q[d+2] * W[(d+2) * K_N + t];
                a3 += q[d+3] * W[(d+3) * K_N + t];
            }
            pk = (a0 + a1) + (a2 + a3);
        }
        const int s  = t >> 5;
        const int g  = (t >> 3) & 3;
        const int j  = t & 7;
        const int mt = b >> 4;
        const int ln = (g << 4) | (b & 15);
        ushort* pa = (ushort*)(ws + WS_PA);
        pa[((mt * 10 + s) * 64 + ln) * 8 + j] = f2bf(pk);
    }

    if (t < L_N) {
        const float r = sqrtf(1.4426950408889634f / var[t]);
        ws[WS_SH + t * 32 + b] = r * (num_lit[(long)e1b * L_N + t] - c[t]);
        ws[WS_W  + t * 32 + b] = nf_w[rb * L_N + t];
        if (b == 0) ws[WS_NR + t] = -r;
    }
    if (t == 300) {
        float s = 0.f;
        for (int d = 0; d < D_N; ++d) s += q[d] * b_lit[d];
        ws[WS_S0 + b] = s;
    }
}

// Block = 32 e-rows (two 16-e tiles); waves = (mt, h). 1250 blocks, 5000 waves.
// Best-known configuration (r17): B-operand/afr loads issued first, async DMA
// staging second, MFMA third, staging barrier after MFMA (its implicit
// vmcnt(0) lands after ~2-3us of compute), RBF on LDS, cbuf aliases mlit.
__global__ __launch_bounds__(256, 3) void score_kernel(
    const float* __restrict__ emb_e, const float* __restrict__ num_lit,
    const float* __restrict__ num_lit_norm, const float* __restrict__ ws,
    float* __restrict__ out)
{
    __shared__ float smem[SM_TOT];

    const int lane = threadIdx.x & 63;
    const int wv   = threadIdx.x >> 6;
    const int mt   = wv & 1;                   // b-half
    const int h    = wv >> 1;                  // l/K half
    const int er   = lane & 15;
    const int g    = lane >> 4;
    const int ea   = blockIdx.x * 32 + er;         // e-tile 0
    const int eb   = ea + 16;                      // e-tile 1
    const int b0   = mt * 16 + 4 * g;

    // ---- (1) issue compute-phase global loads FIRST (r12-proven hoist) ----
    f32x4 acc_a = {0.f, 0.f, 0.f, 0.f};
    f32x4 acc_b = {0.f, 0.f, 0.f, 0.f};
    if (h == 0) {
        acc_a = *(const f32x4*)(ws + WS_S0 + b0);
        acc_b = acc_a;
    }

    s16x8 afr[5];
    {
        const s16x8* pAg = (const s16x8*)(ws + WS_PA);
#pragma unroll
        for (int i = 0; i < 5; ++i) afr[i] = pAg[(mt * 10 + h * 5 + i) * 64 + lane];
    }

    const float* embrA = emb_e        + (long)ea * D_N;
    const float* litnA = num_lit_norm + (long)ea * L_N;
    const float* embrB = emb_e        + (long)eb * D_N;
    const float* litnB = num_lit_norm + (long)eb * L_N;

    f32x4 loA[5], hiA[5], loB[5], hiB[5];
#pragma unroll
    for (int i = 0; i < 4; ++i) {
        const int k0 = 32 * (h * 5 + i) + 8 * g;
        const float* bpA = (k0 < 200) ? (embrA + k0) : (litnA + (k0 - 200));
        const float* bpB = (k0 < 200) ? (embrB + k0) : (litnB + (k0 - 200));
        loA[i] = *(const f32x4*)bpA;
        hiA[i] = *(const f32x4*)(bpA + 4);
        loB[i] = *(const f32x4*)bpB;
        hiB[i] = *(const f32x4*)(bpB + 4);
    }
    if (h == 0) {       // step s=4: k0 = 128+8g, pure embr
        const int k0 = 128 + 8 * g;
        loA[4] = *(const f32x4*)(embrA + k0);
        hiA[4] = *(const f32x4*)(embrA + k0 + 4);
        loB[4] = *(const f32x4*)(embrB + k0);
        hiB[4] = *(const f32x4*)(embrB + k0 + 4);
    } else {            // step s=9: k = 288..319 (real lit 88..99; A zero-pads k>=300)
        f32x4 z = {0.f, 0.f, 0.f, 0.f};
        loA[4] = z; hiA[4] = z; loB[4] = z; hiB[4] = z;
        if (g == 0)      { loA[4] = *(const f32x4*)(litnA + 88); hiA[4] = *(const f32x4*)(litnA + 92);
                           loB[4] = *(const f32x4*)(litnB + 88); hiB[4] = *(const f32x4*)(litnB + 92); }
        else if (g == 1) { loA[4] = *(const f32x4*)(litnA + 96);
                           loB[4] = *(const f32x4*)(litnB + 96); }
    }

    // ---- (2) issue async DMA staging (fire-and-forget until the barrier) ----
    {
        const f32x4* s4  = (const f32x4*)ws;
        const f32x4* ml4 = (const f32x4*)(num_lit + (long)blockIdx.x * 32 * L_N);
        f32x4* d4 = (f32x4*)smem;
        for (int i = threadIdx.x; i < STAGE_N; i += 256) {
            const f32x4* src = (i < 1633) ? (s4 + i) : (ml4 + (i - 1633));
            __builtin_amdgcn_global_load_lds((const __attribute__((address_space(1))) void*)src,
                                             (__attribute__((address_space(3))) void*)(d4 + i),
                                             16, 0, 0);
        }
    }

    // ---- (3) MFMA phase (registers + global data only; no LDS reads) ----
#pragma unroll
    for (int i = 0; i < 5; ++i) {
        acc_a = __builtin_amdgcn_mfma_f32_16x16x32_bf16(afr[i], pack_bf8(loA[i], hiA[i]), acc_a, 0, 0, 0);
        acc_b = __builtin_amdgcn_mfma_f32_16x16x32_bf16(afr[i], pack_bf8(loB[i], hiB[i]), acc_b, 0, 0, 0);
    }

    // ---- (4) barrier: __syncthreads' implicit vmcnt(0) drains the DMA ----
    __syncthreads();

    // ---- (5) score_n: RBF, lc in [13h, h?25:13) — all operands in LDS ----
    const int lc0 = h ? 13 : 0;
    const int lcE = h ? 25 : 13;
    const float* mlA = smem + SM_ML + er * L_N;          // this lane's tile-a row
    const float* mlB = mlA + 16 * L_N;                   // tile-b row
    for (int lc = lc0; lc < lcE; ++lc) {
        const f32x4 mva = *(const f32x4*)(mlA + lc * 4);
        const f32x4 mvb = *(const f32x4*)(mlB + lc * 4);
        const f32x4 nv  = *(const f32x4*)(smem + WS_NR + lc * 4);
#pragma unroll
        for (int ll = 0; ll < 4; ++ll) {
            const int l = lc * 4 + ll;
            const float rma = nv[ll] * mva[ll];
            const float rmb = nv[ll] * mvb[ll];
            f32x4 s4v = *(const f32x4*)(smem + WS_SH + l * 32 + b0);
            f32x4 w4v = *(const f32x4*)(smem + WS_W  + l * 32 + b0);
#pragma unroll
            for (int j = 0; j < 4; ++j) {
                const float ua = rma + s4v[j];
                const float ub = rmb + s4v[j];
                acc_a[j] = fmaf(fast_exp2(-(ua * ua)), w4v[j], acc_a[j]);
                acc_b[j] = fmaf(fast_exp2(-(ub * ub)), w4v[j], acc_b[j]);
            }
        }
    }

    // ---- (6) combine halves + sigmoid + store (cbuf aliases mlit; proven) ----
    float* cbuf = smem + SM_ML;
    __syncthreads();                 // all RBF reads of mlit complete before overwrite
    if (h) {
        *(f32x4*)(cbuf + ((0 * 2 + mt) * 64 + lane) * 4) = acc_a;
        *(f32x4*)(cbuf + ((1 * 2 + mt) * 64 + lane) * 4) = acc_b;
    }
    __syncthreads();
    if (!h) {
        const f32x4 oa = *(const f32x4*)(cbuf + ((0 * 2 + mt) * 64 + lane) * 4);
        const f32x4 ob = *(const f32x4*)(cbuf + ((1 * 2 + mt) * 64 + lane) * 4);
#pragma unroll
        for (int j = 0; j < 4; ++j) {
            const float va = acc_a[j] + oa[j];
            const float za = fast_exp2(va * -1.4426950408889634f);
            out[(long)(b0 + j) * E_N + ea] = fast_rcp(1.0f + za);
            const float vb = acc_b[j] + ob[j];
            const float zb = fast_exp2(vb * -1.4426950408889634f);
            out[(long)(b0 + j) * E_N + eb] = fast_rcp(1.0f + zb);
        }
    }
}

extern "C" void kernel_launch(void* const* d_in, const int* in_sizes, int n_in,
                              void* d_out, int out_size, void* d_ws, size_t ws_size,
                              hipStream_t stream) {
    const int*   e1       = (const int*)d_in[0];
    const int*   rel      = (const int*)d_in[1];
    const float* emb_e    = (const float*)d_in[2];
    const float* emb_rel  = (const float*)d_in[3];
    const float* num_lit  = (const float*)d_in[4];
    const float* num_lit_norm = (const float*)d_in[5];
    const float* W_lit    = (const float*)d_in[6];
    const float* b_lit    = (const float*)d_in[7];
    const float* c        = (const float*)d_in[8];
    const float* var      = (const float*)d_in[9];
    const float* nf_w     = (const float*)d_in[10];
    float* out = (float*)d_out;
    float* ws  = (float*)d_ws;

    hipLaunchKernelGGL(prep_kernel, dim3(B_N), dim3(320), 0, stream,
                       e1, rel, emb_e, emb_rel, num_lit, num_lit_norm,
                       W_lit, b_lit, c, var, nf_w, ws);
    hipLaunchKernelGGL(score_kernel, dim3(1250), dim3(256), 0, stream,
                       emb_e, num_lit, num_lit_norm, ws, out);
}